// Round 7
// baseline (35.769 us; speedup 1.0000x reference)
//
#include <hip/hip_runtime.h>
#include <hip/hip_bf16.h>

#define SLEN 4096
#define NH 16
#define PDIM 64
#define NDIM 128
#define NBH 32   // b*h
#define KSPLIT 16
#define TT 64    // t per LDS tile

typedef __attribute__((ext_vector_type(8))) short short8;
typedef __attribute__((ext_vector_type(4))) float f32x4;

// raw barrier: LDS ordering via lgkmcnt only — does NOT drain vmcnt, so
// register-prefetch global loads stay in flight across the barrier (T4).
#define BAR()                                                                  \
    {                                                                          \
        asm volatile("s_waitcnt lgkmcnt(0)" ::: "memory");                     \
        __builtin_amdgcn_sched_barrier(0);                                     \
        __builtin_amdgcn_s_barrier();                                          \
    }

// swizzle: spreads ds_read_b128 (rows consecutive) and transpose ds_write_b32
// (rows stride-4) across the 8 16B slots of a 128B row
__device__ __forceinline__ int swz(int r) { return ((r & 7) ^ ((r >> 2) & 7)) << 4; }

__device__ __forceinline__ unsigned short f2bfu(float x) {
    __hip_bfloat16 h = __float2bfloat16(x);
    return *reinterpret_cast<unsigned short*>(&h);
}
__device__ __forceinline__ unsigned pack2(float lo, float hi) {
    return (unsigned)f2bfu(lo) | ((unsigned)f2bfu(hi) << 16);
}

// ---------------- Fused kernel: in-block suffix weights + LDS-staged GEMM -----
// out[p, n-half] += sum_t (w[t]*X[t,p]) * B[t,n] over this block's K-slice.
// Grid (ks, ns, bh) = 16x2x32 = 1024 blocks (4/CU). Block: 256 thr = 4 waves
// (2p x 2n), wave = 32p x 32n (2x2 frags of 16x16x32 bf16).
// LDS buffer: X=[64p][64t] bf16 (8KB) + B=[64n][64t] bf16 (8KB), double-buffered
// (32KB + w table). Register prefetch depth 2, lgkm-only barriers.
template <int KB, int NT>
__global__ __launch_bounds__(256, 4) void state_gemm_kernel(
    const float* __restrict__ X, const float* __restrict__ Bm,
    const float* __restrict__ A, float* __restrict__ partial) {
    int ks = blockIdx.x;
    int ns = blockIdx.y;
    int bh = blockIdx.z;
    int b = bh >> 4, h = bh & 15;
    int tid = threadIdx.x;
    int lane = tid & 63, wv_ = tid >> 6;          // 4 waves
    int wp = wv_ & 1, wn = wv_ >> 1;
    int p0 = wp * 32, n0 = wn * 32;               // block-local
    int m = lane & 15, kg = lane >> 4;
    int c = tid & 15, tp = tid >> 4;              // staging: c 0..15, tp 0..15

    __shared__ __align__(16) char lds[2][16384];  // X at 0, B at 8192
    __shared__ float wlds[KB];

    const float* Xb = X + (size_t)b * (SLEN * NH * PDIM) + h * PDIM;
    const float* Bb = Bm + (size_t)b * (SLEN * NH * NDIM) + h * NDIM + ns * 64;
    const float* Ab = A + (size_t)b * (SLEN * NH) + h;  // stride NH
    int t0 = ks * KB;

    const float* xsrc = Xb + (size_t)(t0 + 2 * tp) * (NH * PDIM) + 4 * c;
    const float* bsrc = Bb + (size_t)(t0 + 2 * tp) * (NH * NDIM) + 4 * c;

    // staging write byte offsets: row r=4c+i, t-pair tp; second t-half (tp+16)
    // is wX[i]^64 (bit 6 clear in base, XOR-safe vs swizzle bits).
    int wX[4];
#pragma unroll
    for (int i = 0; i < 4; ++i) {
        int r = 4 * c + i;
        wX[i] = (r * 128 + 4 * tp) ^ swz(r);
    }
    // fragment read byte offsets
    int rA[2][2], rB[2][2];
#pragma unroll
    for (int pi = 0; pi < 2; ++pi)
#pragma unroll
        for (int kk = 0; kk < 2; ++kk) {
            int r = p0 + pi * 16 + m;
            rA[pi][kk] = (r * 128 + kk * 64 + kg * 16) ^ swz(r);
        }
#pragma unroll
    for (int ni = 0; ni < 2; ++ni)
#pragma unroll
        for (int kk = 0; kk < 2; ++kk) {
            int rn = n0 + ni * 16 + m;
            rB[ni][kk] = 8192 + ((rn * 128 + kk * 64 + kg * 16) ^ swz(rn));
        }

    f32x4 acc[2][2];
#pragma unroll
    for (int i = 0; i < 2; ++i)
#pragma unroll
        for (int j = 0; j < 2; ++j) acc[i][j] = (f32x4){0.f, 0.f, 0.f, 0.f};

    // two register banks for depth-2 prefetch (8 f32x4 per bank)
    f32x4 xa[2], xb[2], xc[2], xd[2], ba[2], bb_[2], bc[2], bd[2];

#define LOADR(it, bk)                                                          \
    {                                                                          \
        const float* xp = xsrc + (size_t)(it) * (TT * NH * PDIM);              \
        const float* bp = bsrc + (size_t)(it) * (TT * NH * NDIM);              \
        xa[bk] = *(const f32x4*)(xp);                                          \
        xb[bk] = *(const f32x4*)(xp + NH * PDIM);                              \
        xc[bk] = *(const f32x4*)(xp + 32 * NH * PDIM);                         \
        xd[bk] = *(const f32x4*)(xp + 33 * NH * PDIM);                         \
        ba[bk] = *(const f32x4*)(bp);                                          \
        bb_[bk] = *(const f32x4*)(bp + NH * NDIM);                             \
        bc[bk] = *(const f32x4*)(bp + 32 * NH * NDIM);                         \
        bd[bk] = *(const f32x4*)(bp + 33 * NH * NDIM);                         \
    }

#define CVTW(buf, bk, it)                                                      \
    {                                                                          \
        float w0 = wlds[(it) * TT + 2 * tp];                                   \
        float w1 = wlds[(it) * TT + 2 * tp + 1];                               \
        float w2 = wlds[(it) * TT + 2 * tp + 32];                              \
        float w3 = wlds[(it) * TT + 2 * tp + 33];                              \
        char* dst = lds[buf];                                                  \
        _Pragma("unroll") for (int i = 0; i < 4; ++i) {                        \
            *(unsigned*)(dst + wX[i]) = pack2(xa[bk][i] * w0, xb[bk][i] * w1); \
            *(unsigned*)(dst + (wX[i] ^ 64)) = pack2(xc[bk][i] * w2, xd[bk][i] * w3); \
            *(unsigned*)(dst + wX[i] + 8192) = pack2(ba[bk][i], bb_[bk][i]);   \
            *(unsigned*)(dst + (wX[i] ^ 64) + 8192) = pack2(bc[bk][i], bd[bk][i]); \
        }                                                                      \
    }

#define COMPUTE(buf)                                                           \
    {                                                                          \
        const char* src = lds[buf];                                            \
        short8 af[2][2], bf[2][2];                                             \
        _Pragma("unroll") for (int pi = 0; pi < 2; ++pi)                       \
            _Pragma("unroll") for (int kk = 0; kk < 2; ++kk)                   \
                af[pi][kk] = *(const short8*)(src + rA[pi][kk]);               \
        _Pragma("unroll") for (int ni = 0; ni < 2; ++ni)                       \
            _Pragma("unroll") for (int kk = 0; kk < 2; ++kk)                   \
                bf[ni][kk] = *(const short8*)(src + rB[ni][kk]);               \
        _Pragma("unroll") for (int kk = 0; kk < 2; ++kk)                       \
            _Pragma("unroll") for (int pi = 0; pi < 2; ++pi)                   \
                _Pragma("unroll") for (int ni = 0; ni < 2; ++ni)               \
                    acc[pi][ni] = __builtin_amdgcn_mfma_f32_16x16x32_bf16(     \
                        af[pi][kk], bf[ni][kk], acc[pi][ni], 0, 0, 0);         \
    }

    // prologue: put 16 loads (2 tiles) in flight before anything else
    LOADR(0, 0);
    if (NT > 1) LOADR(1, 1);

    // ---- suffix weights via wave shfl scan (hides under the in-flight loads)
    {
        float* sc = (float*)(lds[1]);  // 8-float scratch; lds[1] unwritten yet
        float ts = 0.f;
        for (int t = t0 + KB + tid; t < SLEN; t += 256) ts += Ab[(size_t)t * NH];
        constexpr int E = (KB + 255) / 256;
        float loc[E];
        float run = 0.f;
        int base = tid * E;
#pragma unroll
        for (int e = 0; e < E; ++e) {
            int idx = base + e;
            if (idx < KB) { run += Ab[(size_t)(t0 + idx) * NH]; loc[e] = run; }
        }
        float v = run;
#pragma unroll
        for (int off = 1; off < 64; off <<= 1) {
            float u = __shfl_up(v, off, 64);
            if (lane >= off) v += u;
        }
#pragma unroll
        for (int off = 32; off > 0; off >>= 1) ts += __shfl_xor(ts, off, 64);
        if (lane == 63) sc[wv_] = v;       // per-wave slice sum
        if (lane == 0) sc[4 + wv_] = ts;   // per-wave tail sum
        BAR();
        float woff = 0.f, tot = 0.f, stail = 0.f;
#pragma unroll
        for (int q = 0; q < 4; ++q) {
            float s_ = sc[q];
            tot += s_;
            if (q < wv_) woff += s_;
            stail += sc[4 + q];
        }
        float excl = woff + v - run;
        float basew = stail + tot;
#pragma unroll
        for (int e = 0; e < E; ++e) {
            int idx = base + e;
            if (idx < KB) wlds[idx] = expf(basew - (excl + loc[e]));
        }
        BAR();
    }

    CVTW(0, 0, 0);
    BAR();

#pragma unroll
    for (int it = 0; it < NT; ++it) {
        if (it + 2 < NT) LOADR(it + 2, it & 1);        // issue 2 tiles ahead
        COMPUTE(it & 1);                                // tile it lives in buf it&1
        if (it + 1 < NT) CVTW((it + 1) & 1, (it + 1) & 1, it + 1);
        BAR();  // lgkm-only: prefetch vmcnt stays in flight across the barrier
    }
#undef LOADR
#undef CVTW
#undef COMPUTE

    float* outp = partial + ((size_t)ks * NBH + bh) * (PDIM * NDIM) + ns * 64;
#pragma unroll
    for (int pi = 0; pi < 2; ++pi)
#pragma unroll
        for (int ni = 0; ni < 2; ++ni)
#pragma unroll
            for (int r = 0; r < 4; ++r) {
                int p = p0 + pi * 16 + kg * 4 + r;  // C/D: row=(lane>>4)*4+reg
                int n = n0 + ni * 16 + m;           // C/D: col=lane&15 (block-local)
                outp[p * NDIM + n] = acc[pi][ni][r];
            }
}

// ---------------- Kernel 2: reduce K-split partials (float4) -------------------
__global__ void reduce_kernel(const float* __restrict__ partial, float* __restrict__ out,
                              int ksplit) {
    int i = blockIdx.x * 256 + threadIdx.x;  // float4 index
    const f32x4* pp = (const f32x4*)partial;
    f32x4 s = (f32x4){0.f, 0.f, 0.f, 0.f};
    for (int ks = 0; ks < ksplit; ++ks) {
        f32x4 v = pp[(size_t)ks * (NBH * PDIM * NDIM / 4) + i];
        s.x += v.x; s.y += v.y; s.z += v.z; s.w += v.w;
    }
    ((f32x4*)out)[i] = s;
}

extern "C" void kernel_launch(void* const* d_in, const int* in_sizes, int n_in,
                              void* d_out, int out_size, void* d_ws, size_t ws_size,
                              hipStream_t stream) {
    const float* X = (const float*)d_in[0];
    const float* A = (const float*)d_in[1];
    const float* Bm = (const float*)d_in[2];
    // d_in[3] (C) is unused by the reference.
    float* out = (float*)d_out;

    float* partial = (float*)d_ws;
    size_t slice_bytes = (size_t)NBH * PDIM * NDIM * sizeof(float);

    if (ws_size < (size_t)KSPLIT * slice_bytes) {
        // degenerate fallback: single K-slice (full sequence) straight into out
        state_gemm_kernel<SLEN, SLEN / TT><<<dim3(1, 2, NBH), 256, 0, stream>>>(X, Bm, A, out);
        return;
    }
    state_gemm_kernel<SLEN / KSPLIT, SLEN / KSPLIT / TT>
        <<<dim3(KSPLIT, 2, NBH), 256, 0, stream>>>(X, Bm, A, partial);
    int nout4 = NBH * PDIM * NDIM / 4;
    reduce_kernel<<<nout4 / 256, 256, 0, stream>>>(partial, out, KSPLIT);
}